// Round 4
// baseline (159.598 us; speedup 1.0000x reference)
//
#include <hip/hip_runtime.h>

// Shapes: x[2,16,1024,512] f32, past_kv[2,16,64,64] f32, Wq/Wk/Wv[64,512], b*[64]
// Outputs (concat): out[2,16,1024,64] (group-normed), current_kv[2,16,1024,64,64]

constexpr int B  = 2;
constexpr int NH = 16;
constexpr int L  = 1024;
constexpr int E  = 512;
constexpr int D  = 64;
constexpr int M  = B * NH * L;     // 32768 rows
constexpr int NQKV = 192;
constexpr int BLK = 16;            // positions per fused block
constexpr int NBLKS = M / BLK;     // 2048
constexpr float EPS = 1e-5f;

using short8 = __attribute__((ext_vector_type(8))) short;
using f32x4  = __attribute__((ext_vector_type(4))) float;

__device__ __forceinline__ unsigned short f2bf(float f) {
    union { float f; unsigned int u; } x; x.f = f;
    unsigned int u = x.u;
    return (unsigned short)((u + 0x7fffu + ((u >> 16) & 1u)) >> 16);
}

// ---------------------------------------------------------------------------
// Kernel 0: convert Wq|Wk|Wv (each 64x512 f32) -> Wb bf16 [192][512] (in ws)
// ---------------------------------------------------------------------------
__global__ __launch_bounds__(256) void convw_kernel(
    const float* __restrict__ Wq, const float* __restrict__ Wk,
    const float* __restrict__ Wv, unsigned short* __restrict__ Wb)
{
    int idx = blockIdx.x * 256 + threadIdx.x;      // float4 index, 0..24575
    const float* src = (idx < 8192) ? Wq : (idx < 16384) ? Wk : Wv;
    int off = idx & 8191;
    float4 v = ((const float4*)src)[off];
    Wb[(size_t)idx * 4 + 0] = f2bf(v.x);
    Wb[(size_t)idx * 4 + 1] = f2bf(v.y);
    Wb[(size_t)idx * 4 + 2] = f2bf(v.z);
    Wb[(size_t)idx * 4 + 3] = f2bf(v.w);
}

// ---------------------------------------------------------------------------
// Kernel 1: FUSED proj + retention. One block per 16 positions of one (b,n).
//  1. stage X[16][512] -> bf16 LDS
//  2. qkv[16][192] = X @ Wb^T + bias   (MFMA, B-frags from L2)
//  3. ckv = decay*pkv + k (x) v        (pkv slots in registers from L2)
//  4. out_pre = decay*(q@pkv) + (q.k)*v, block groupnorm partials
// ---------------------------------------------------------------------------
__global__ __launch_bounds__(256) void fused_kernel(
    const float* __restrict__ x,        // [M,512]
    const unsigned short* __restrict__ Wb, // [192][512] bf16
    const float* __restrict__ bq, const float* __restrict__ bk,
    const float* __restrict__ bv,
    const float* __restrict__ past_kv,  // [B*NH, 64, 64]
    float* __restrict__ out_pre,        // [M,64]
    float* __restrict__ ckv,            // [M,4096]
    float* __restrict__ partials)       // [NBLKS,2]
{
    constexpr int LDP = 520;            // bf16 pad: 1040B row -> 2-way banks max
    __shared__ unsigned short Xs[BLK][LDP];    // 16.6 KB
    __shared__ float qkv_s[BLK * NQKV];        // 12 KB
    __shared__ float bias_s[NQKV];
    __shared__ float qk_s[BLK];
    __shared__ float r1[256], r2[256];

    const int blk  = blockIdx.x;
    const int bn   = blk >> 6;             // 64 blocks per (b,n)
    const int pos0 = (blk & 63) * BLK;
    const int h    = bn & (NH - 1);
    const int tid  = threadIdx.x;
    const float decay = 1.0f - exp2f(-5.0f - (float)h);

    if (tid < NQKV)
        bias_s[tid] = (tid < 64) ? bq[tid] : (tid < 128) ? bk[tid - 64] : bv[tid - 128];

    // ---- stage X tile (16 rows x 512) as bf16 ----
    const float* xrow = x + (size_t)(bn * L + pos0) * E;
    #pragma unroll
    for (int j = 0; j < 8; ++j) {
        int f   = tid + j * 256;           // float4 index 0..2047
        int row = f >> 7;                  // 128 float4 per row
        int c4  = f & 127;
        float4 xv = *(const float4*)&xrow[f * 4];
        unsigned short hlf[4] = {f2bf(xv.x), f2bf(xv.y), f2bf(xv.z), f2bf(xv.w)};
        *(uint2*)&Xs[row][c4 * 4] = *(uint2*)hlf;
    }

    // pkv slots for the store phase (coalesced, L2-resident)
    const float* pkv = past_kv + (size_t)bn * 4096;
    float4 p4[4];
    #pragma unroll
    for (int j = 0; j < 4; ++j)
        p4[j] = *(const float4*)&pkv[(tid + j * 256) * 4];

    __syncthreads();

    // ---- MFMA: each wave computes 16 rows x 48 cols ----
    const int wid  = tid >> 6;
    const int lane = tid & 63;
    const int l15  = lane & 15;
    const int lkE  = (lane >> 4) * 8;      // k sub-offset in elements

    f32x4 acc[3] = {};
    #pragma unroll 4
    for (int kt = 0; kt < 16; ++kt) {
        short8 a = *(const short8*)&Xs[l15][kt * 32 + lkE];
        #pragma unroll
        for (int ni = 0; ni < 3; ++ni) {
            int col = wid * 48 + ni * 16 + l15;
            short8 b = *(const short8*)&Wb[(size_t)col * E + kt * 32 + lkE];
            acc[ni] = __builtin_amdgcn_mfma_f32_16x16x32_bf16(a, b, acc[ni], 0, 0, 0);
        }
    }
    #pragma unroll
    for (int ni = 0; ni < 3; ++ni) {
        int col = wid * 48 + ni * 16 + l15;
        float bb = bias_s[col];
        #pragma unroll
        for (int j = 0; j < 4; ++j) {
            int pos = (lane >> 4) * 4 + j;
            qkv_s[pos * NQKV + col] = acc[ni][j] + bb;
        }
    }
    __syncthreads();

    // ---- q.k per position ----
    {
        int pos = tid >> 4, c = tid & 15;
        const float* qp = &qkv_s[pos * NQKV];
        float p = 0.0f;
        #pragma unroll
        for (int j = 0; j < 4; ++j)
            p = fmaf(qp[c * 4 + j], qp[64 + c * 4 + j], p);
        p += __shfl_xor(p, 1); p += __shfl_xor(p, 2);
        p += __shfl_xor(p, 4); p += __shfl_xor(p, 8);
        if (c == 0) qk_s[pos] = p;
    }
    __syncthreads();

    // ---- ckv stores: 16 pos x 16 KB contiguous ----
    float* co = ckv + (size_t)(bn * L + pos0) * 4096;
    for (int pos = 0; pos < BLK; ++pos) {
        const float* ks = &qkv_s[pos * NQKV + 64];
        const float* vs = &qkv_s[pos * NQKV + 128];
        #pragma unroll
        for (int j = 0; j < 4; ++j) {
            int f = tid + j * 256;
            float kk = ks[f >> 4];
            float4 vv = *(const float4*)&vs[(f & 15) * 4];
            float4 r;
            r.x = fmaf(decay, p4[j].x, kk * vv.x);
            r.y = fmaf(decay, p4[j].y, kk * vv.y);
            r.z = fmaf(decay, p4[j].z, kk * vv.z);
            r.w = fmaf(decay, p4[j].w, kk * vv.w);
            *(float4*)&co[(size_t)pos * 4096 + f * 4] = r;
        }
    }

    // ---- out: thread -> vd = tid&63, positions wave, wave+4, wave+8, wave+12
    const int wave = tid >> 6, vd = tid & 63;
    float accs[4] = {0.0f, 0.0f, 0.0f, 0.0f};
    #pragma unroll 8
    for (int kd = 0; kd < 64; ++kd) {
        float pv = pkv[kd * 64 + vd];      // coalesced, L2-hit
        #pragma unroll
        for (int pp = 0; pp < 4; ++pp)
            accs[pp] = fmaf(qkv_s[(wave + pp * 4) * NQKV + kd], pv, accs[pp]);
    }
    float s1 = 0.0f, s2 = 0.0f;
    #pragma unroll
    for (int pp = 0; pp < 4; ++pp) {
        int pos = wave + pp * 4;
        float o = fmaf(decay, accs[pp],
                       qk_s[pos] * qkv_s[pos * NQKV + 128 + vd]);
        out_pre[(size_t)(bn * L + pos0 + pos) * D + vd] = o;
        s1 += o; s2 += o * o;
    }

    r1[tid] = s1; r2[tid] = s2;
    __syncthreads();
    for (int off = 128; off; off >>= 1) {
        if (tid < off) { r1[tid] += r1[tid + off]; r2[tid] += r2[tid + off]; }
        __syncthreads();
    }
    if (tid == 0) {
        partials[(size_t)blk * 2]     = r1[0];
        partials[(size_t)blk * 2 + 1] = r2[0];
    }
}

// ---------------------------------------------------------------------------
// Kernel 2: per-group (b,n) reduction: 64 partials per group, one wave each
// ---------------------------------------------------------------------------
__global__ __launch_bounds__(64) void group_reduce_kernel(
    const float* __restrict__ partials, float* __restrict__ stats)
{
    const int g   = blockIdx.x;   // 0..31
    const int tid = threadIdx.x;  // 0..63
    float s1 = partials[(size_t)(g * 64 + tid) * 2];
    float s2 = partials[(size_t)(g * 64 + tid) * 2 + 1];
    #pragma unroll
    for (int off = 32; off; off >>= 1) {
        s1 += __shfl_down(s1, off);
        s2 += __shfl_down(s2, off);
    }
    if (tid == 0) {
        const float cnt = (float)(L * D);
        float mean = s1 / cnt;
        float var  = s2 / cnt - mean * mean;
        stats[g * 2]     = mean;
        stats[g * 2 + 1] = rsqrtf(var + EPS);
    }
}

// ---------------------------------------------------------------------------
// Kernel 3: in-place normalize (float4)
// ---------------------------------------------------------------------------
__global__ __launch_bounds__(256) void normalize_kernel(
    float* __restrict__ out, const float* __restrict__ stats)
{
    int idx = blockIdx.x * 256 + threadIdx.x;   // float4 index
    int g = idx >> 14;                          // 16384 float4 per group
    float mean = stats[g * 2];
    float rstd = stats[g * 2 + 1];
    float4 v = ((const float4*)out)[idx];
    v.x = (v.x - mean) * rstd; v.y = (v.y - mean) * rstd;
    v.z = (v.z - mean) * rstd; v.w = (v.w - mean) * rstd;
    ((float4*)out)[idx] = v;
}

// ---------------------------------------------------------------------------
extern "C" void kernel_launch(void* const* d_in, const int* in_sizes, int n_in,
                              void* d_out, int out_size, void* d_ws, size_t ws_size,
                              hipStream_t stream)
{
    const float* x       = (const float*)d_in[0];
    const float* past_kv = (const float*)d_in[1];
    const float* Wq      = (const float*)d_in[2];
    const float* bq      = (const float*)d_in[3];
    const float* Wk      = (const float*)d_in[4];
    const float* bk      = (const float*)d_in[5];
    const float* Wv      = (const float*)d_in[6];
    const float* bv      = (const float*)d_in[7];

    float* out = (float*)d_out;                    // [M*64]
    float* ckv = out + (size_t)M * 64;             // [M*4096]

    unsigned short* Wb = (unsigned short*)d_ws;            // 192*512 bf16
    float* partials = (float*)(Wb + (size_t)NQKV * E);     // NBLKS*2
    float* stats    = partials + (size_t)NBLKS * 2;        // 64

    convw_kernel<<<96, 256, 0, stream>>>(Wq, Wk, Wv, Wb);
    fused_kernel<<<NBLKS, 256, 0, stream>>>(x, Wb, bq, bk, bv, past_kv,
                                            out, ckv, partials);
    group_reduce_kernel<<<32, 64, 0, stream>>>(partials, stats);
    normalize_kernel<<<(M * 16) / 256, 256, 0, stream>>>(out, stats);
}

// Round 5
// 139.679 us; speedup vs baseline: 1.1426x; 1.1426x over previous
//
#include <hip/hip_runtime.h>

// Shapes: x[2,16,1024,512] f32, past_kv[2,16,64,64] f32, Wq/Wk/Wv[64,512], b*[64]
// Outputs (concat): out [2,16,1024,64] (group-normed), current_kv [2,16,1024,64,64]

constexpr int B  = 2;
constexpr int NH = 16;
constexpr int L  = 1024;
constexpr int E  = 512;
constexpr int D  = 64;
constexpr int M  = B * NH * L;     // 32768 rows
constexpr int NQKV = 192;
constexpr int BLK = 32;            // positions per retention block
constexpr int NBLKS = M / BLK;     // 1024
constexpr float EPS = 1e-5f;

using short8 = __attribute__((ext_vector_type(8))) short;
using f32x4  = __attribute__((ext_vector_type(4))) float;

__device__ __forceinline__ unsigned short f2bf(float f) {
    union { float f; unsigned int u; } x; x.f = f;
    unsigned int u = x.u;
    return (unsigned short)((u + 0x7fffu + ((u >> 16) & 1u)) >> 16);
}
__device__ __forceinline__ float bf2f(unsigned short h) {
    union { unsigned int u; float f; } x; x.u = ((unsigned int)h) << 16;
    return x.f;
}

// ---------------------------------------------------------------------------
// Kernel 0: convert Wq|Wk|Wv (each 64x512 f32) -> Wb bf16 [192][512] (in ws)
// ---------------------------------------------------------------------------
__global__ __launch_bounds__(256) void convw_kernel(
    const float* __restrict__ Wq, const float* __restrict__ Wk,
    const float* __restrict__ Wv, unsigned short* __restrict__ Wb)
{
    int idx = blockIdx.x * 256 + threadIdx.x;      // float4 index, 0..24575
    const float* src = (idx < 8192) ? Wq : (idx < 16384) ? Wk : Wv;
    int off = idx & 8191;
    float4 v = ((const float4*)src)[off];
    Wb[(size_t)idx * 4 + 0] = f2bf(v.x);
    Wb[(size_t)idx * 4 + 1] = f2bf(v.y);
    Wb[(size_t)idx * 4 + 2] = f2bf(v.z);
    Wb[(size_t)idx * 4 + 3] = f2bf(v.w);
}

// ---------------------------------------------------------------------------
// Kernel 1: QKV projection via bf16 MFMA -> bf16 qkv.
// C[M,192] = X[M,512] * Wb^T + bias.  BM=128, BN=192(all), BK=64.
// ---------------------------------------------------------------------------
__global__ __launch_bounds__(512) void proj_mfma_kernel(
    const float* __restrict__ x, const unsigned short* __restrict__ Wb,
    const float* __restrict__ bq, const float* __restrict__ bk,
    const float* __restrict__ bv,
    unsigned short* __restrict__ qkvb)   // [M,192] bf16
{
    constexpr int BM = 128, BK = 64, LDP = 72;
    __shared__ unsigned short Xs[BM][LDP];
    __shared__ unsigned short Ws[NQKV][LDP];
    __shared__ float bias_s[NQKV];

    const int tid  = threadIdx.x;
    const int row0 = blockIdx.x * BM;
    if (tid < NQKV)
        bias_s[tid] = (tid < 64) ? bq[tid] : (tid < 128) ? bk[tid - 64] : bv[tid - 128];

    const int wid  = tid >> 6;
    const int lane = tid & 63;
    const int wr   = wid >> 2;
    const int wc   = wid & 3;
    const int l15  = lane & 15;
    const int lk   = (lane >> 4) * 8;

    const int xr = tid >> 2;
    const int xc = (tid & 3) * 16;

    f32x4 acc[4][3] = {};

    for (int k0 = 0; k0 < E; k0 += BK) {
        float4 xa[4];
        #pragma unroll
        for (int i = 0; i < 4; ++i)
            xa[i] = *(const float4*)&x[(size_t)(row0 + xr) * E + k0 + xc + i * 4];
        short8 wch[3];
        #pragma unroll
        for (int i = 0; i < 3; ++i) {
            int c = tid + i * 512;
            wch[i] = *(const short8*)&Wb[(size_t)(c >> 3) * E + k0 + (c & 7) * 8];
        }
        __syncthreads();
        unsigned short tmp[16];
        #pragma unroll
        for (int i = 0; i < 4; ++i) {
            tmp[i*4+0] = f2bf(xa[i].x); tmp[i*4+1] = f2bf(xa[i].y);
            tmp[i*4+2] = f2bf(xa[i].z); tmp[i*4+3] = f2bf(xa[i].w);
        }
        *(short8*)&Xs[xr][xc]     = *(short8*)&tmp[0];
        *(short8*)&Xs[xr][xc + 8] = *(short8*)&tmp[8];
        #pragma unroll
        for (int i = 0; i < 3; ++i) {
            int c = tid + i * 512;
            *(short8*)&Ws[c >> 3][(c & 7) * 8] = wch[i];
        }
        __syncthreads();

        #pragma unroll
        for (int kk = 0; kk < 2; ++kk) {
            short8 a[4], b[3];
            #pragma unroll
            for (int mi = 0; mi < 4; ++mi)
                a[mi] = *(const short8*)&Xs[wr * 64 + mi * 16 + l15][kk * 32 + lk];
            #pragma unroll
            for (int ni = 0; ni < 3; ++ni)
                b[ni] = *(const short8*)&Ws[wc * 48 + ni * 16 + l15][kk * 32 + lk];
            #pragma unroll
            for (int mi = 0; mi < 4; ++mi)
                #pragma unroll
                for (int ni = 0; ni < 3; ++ni)
                    acc[mi][ni] = __builtin_amdgcn_mfma_f32_16x16x32_bf16(
                        a[mi], b[ni], acc[mi][ni], 0, 0, 0);
        }
    }

    #pragma unroll
    for (int mi = 0; mi < 4; ++mi) {
        #pragma unroll
        for (int ni = 0; ni < 3; ++ni) {
            int col = wc * 48 + ni * 16 + l15;
            float bb = bias_s[col];
            #pragma unroll
            for (int j = 0; j < 4; ++j) {
                int row = wr * 64 + mi * 16 + (lane >> 4) * 4 + j;
                qkvb[(size_t)(row0 + row) * NQKV + col] = f2bf(acc[mi][ni][j] + bb);
            }
        }
    }
}

// ---------------------------------------------------------------------------
// Kernel 2: fused retention, 32 positions / block, 512 threads, 1024 blocks.
//   Exactly 4 blocks x 8 waves per CU = 32 waves/CU.
// ---------------------------------------------------------------------------
__global__ __launch_bounds__(512) void retention_kernel(
    const unsigned short* __restrict__ qkvb,  // [M,192] bf16
    const float* __restrict__ past_kv,        // [B*NH, 64, 64]
    float* __restrict__ out_pre,              // [M,64]
    float* __restrict__ ckv,                  // [M,4096]
    float* __restrict__ partials)             // [NBLKS,2]
{
    const int blk  = blockIdx.x;
    const int bn   = blk >> 5;             // 32 blocks per (b,n)
    const int pos0 = (blk & 31) * BLK;
    const int h    = bn & (NH - 1);
    const int tid  = threadIdx.x;
    const float decay = 1.0f - exp2f(-5.0f - (float)h);

    __shared__ float pkv_s[64 * 64];               // 16 KB
    __shared__ unsigned short qkv_s[BLK * NQKV];   // 12 KB
    __shared__ float qk_s[BLK];
    __shared__ float red[16];

    // ---- stage past_kv (keep this thread's store slots in regs too) ----
    const float* pkv = past_kv + (size_t)bn * 4096;
    float4 p4[2];
    #pragma unroll
    for (int j = 0; j < 2; ++j) {
        p4[j] = *(const float4*)&pkv[(tid + j * 512) * 4];
        *(float4*)&pkv_s[(tid + j * 512) * 4] = p4[j];
    }
    // ---- stage qkv rows (bf16): 32*192 ushorts = 768 uint4 ----
    const unsigned short* qrow = qkvb + (size_t)(bn * L + pos0) * NQKV;
    for (int f = tid; f < 768; f += 512)
        ((uint4*)qkv_s)[f] = ((const uint4*)qrow)[f];
    __syncthreads();

    // ---- q.k per position: pos = tid>>4, chunk c = tid&15 (4 elems) ----
    {
        int pos = tid >> 4, c = tid & 15;
        const unsigned short* qp = &qkv_s[pos * NQKV];
        float p = 0.0f;
        #pragma unroll
        for (int j = 0; j < 4; ++j)
            p = fmaf(bf2f(qp[c * 4 + j]), bf2f(qp[64 + c * 4 + j]), p);
        p += __shfl_xor(p, 1); p += __shfl_xor(p, 2);
        p += __shfl_xor(p, 4); p += __shfl_xor(p, 8);
        if (c == 0) qk_s[pos] = p;
    }

    // ---- ckv stores: 32 pos x 16 KB contiguous ----
    float* co = ckv + (size_t)(bn * L + pos0) * 4096;
    for (int pos = 0; pos < BLK; ++pos) {
        const unsigned short* ks = &qkv_s[pos * NQKV + 64];
        const unsigned short* vs = &qkv_s[pos * NQKV + 128];
        #pragma unroll
        for (int j = 0; j < 2; ++j) {
            int f = tid + j * 512;           // float4 slot 0..1023
            float kk = bf2f(ks[f >> 4]);
            const unsigned short* vp = &vs[(f & 15) * 4];
            float4 r;
            r.x = fmaf(decay, p4[j].x, kk * bf2f(vp[0]));
            r.y = fmaf(decay, p4[j].y, kk * bf2f(vp[1]));
            r.z = fmaf(decay, p4[j].z, kk * bf2f(vp[2]));
            r.w = fmaf(decay, p4[j].w, kk * bf2f(vp[3]));
            *(float4*)&co[(size_t)pos * 4096 + f * 4] = r;
        }
    }
    __syncthreads();   // qk_s ready for all waves

    // ---- out: wave = tid>>6 (0..7), vd = tid&63; pos = wave + pp*8 ----
    const int wave = tid >> 6, lane = tid & 63;
    const int vd = lane;
    float accs[4] = {0.0f, 0.0f, 0.0f, 0.0f};
    for (int kd = 0; kd < 64; ++kd) {
        float pv = pkv_s[kd * 64 + vd];
        #pragma unroll
        for (int pp = 0; pp < 4; ++pp)
            accs[pp] = fmaf(bf2f(qkv_s[(wave + pp * 8) * NQKV + kd]), pv, accs[pp]);
    }
    float s1 = 0.0f, s2 = 0.0f;
    #pragma unroll
    for (int pp = 0; pp < 4; ++pp) {
        int pos = wave + pp * 8;
        float o = fmaf(decay, accs[pp],
                       qk_s[pos] * bf2f(qkv_s[pos * NQKV + 128 + vd]));
        out_pre[(size_t)(bn * L + pos0 + pos) * D + vd] = o;
        s1 += o; s2 += o * o;
    }

    // ---- block partials: wave shuffle-reduce, then 8-way LDS combine ----
    #pragma unroll
    for (int off = 32; off; off >>= 1) {
        s1 += __shfl_down(s1, off);
        s2 += __shfl_down(s2, off);
    }
    if (lane == 0) { red[wave * 2] = s1; red[wave * 2 + 1] = s2; }
    __syncthreads();
    if (tid == 0) {
        float a = 0.0f, b2 = 0.0f;
        #pragma unroll
        for (int w = 0; w < 8; ++w) { a += red[w * 2]; b2 += red[w * 2 + 1]; }
        partials[(size_t)blk * 2]     = a;
        partials[(size_t)blk * 2 + 1] = b2;
    }
}

// ---------------------------------------------------------------------------
// Kernel 3: per-group (b,n) reduction: 32 partials per group, one wave each
// ---------------------------------------------------------------------------
__global__ __launch_bounds__(64) void group_reduce_kernel(
    const float* __restrict__ partials, float* __restrict__ stats)
{
    const int g   = blockIdx.x;   // 0..31
    const int tid = threadIdx.x;  // 0..63
    float s1 = 0.0f, s2 = 0.0f;
    if (tid < 32) {
        s1 = partials[(size_t)(g * 32 + tid) * 2];
        s2 = partials[(size_t)(g * 32 + tid) * 2 + 1];
    }
    #pragma unroll
    for (int off = 16; off; off >>= 1) {
        s1 += __shfl_down(s1, off);
        s2 += __shfl_down(s2, off);
    }
    if (tid == 0) {
        const float cnt = (float)(L * D);
        float mean = s1 / cnt;
        float var  = s2 / cnt - mean * mean;
        stats[g * 2]     = mean;
        stats[g * 2 + 1] = rsqrtf(var + EPS);
    }
}

// ---------------------------------------------------------------------------
// Kernel 4: in-place normalize (float4)
// ---------------------------------------------------------------------------
__global__ __launch_bounds__(256) void normalize_kernel(
    float* __restrict__ out, const float* __restrict__ stats)
{
    int idx = blockIdx.x * 256 + threadIdx.x;   // float4 index
    int g = idx >> 14;                          // 16384 float4 per group
    float mean = stats[g * 2];
    float rstd = stats[g * 2 + 1];
    float4 v = ((const float4*)out)[idx];
    v.x = (v.x - mean) * rstd; v.y = (v.y - mean) * rstd;
    v.z = (v.z - mean) * rstd; v.w = (v.w - mean) * rstd;
    ((float4*)out)[idx] = v;
}

// ---------------------------------------------------------------------------
extern "C" void kernel_launch(void* const* d_in, const int* in_sizes, int n_in,
                              void* d_out, int out_size, void* d_ws, size_t ws_size,
                              hipStream_t stream)
{
    const float* x       = (const float*)d_in[0];
    const float* past_kv = (const float*)d_in[1];
    const float* Wq      = (const float*)d_in[2];
    const float* bq      = (const float*)d_in[3];
    const float* Wk      = (const float*)d_in[4];
    const float* bk      = (const float*)d_in[5];
    const float* Wv      = (const float*)d_in[6];
    const float* bv      = (const float*)d_in[7];

    float* out = (float*)d_out;                    // [M*64]
    float* ckv = out + (size_t)M * 64;             // [M*4096]

    unsigned short* Wb   = (unsigned short*)d_ws;              // 192*512 bf16
    unsigned short* qkvb = Wb + (size_t)NQKV * E;              // M*192 bf16
    float* partials = (float*)(qkvb + (size_t)M * NQKV);       // NBLKS*2
    float* stats    = partials + (size_t)NBLKS * 2;            // 64

    convw_kernel<<<96, 256, 0, stream>>>(Wq, Wk, Wv, Wb);
    proj_mfma_kernel<<<M / 128, 512, 0, stream>>>(x, Wb, bq, bk, bv, qkvb);
    retention_kernel<<<NBLKS, 512, 0, stream>>>(qkvb, past_kv, out, ckv, partials);
    group_reduce_kernel<<<32, 64, 0, stream>>>(partials, stats);
    normalize_kernel<<<(M * 16) / 256, 256, 0, stream>>>(out, stats);
}